// Round 1
// baseline (1006.710 us; speedup 1.0000x reference)
//
#include <hip/hip_runtime.h>

#define BSZ 16
#define NN 1024
#define FE 64
#define HD 128
#define NIT 4
#define TI 16

__device__ __forceinline__ float4 ld4(const float* p) { return *(const float4*)p; }

// ---------------- row-MLP: out[row,:] = relu( [in1(,in2)] @ W + b ) ----------------
// 64 rows per block, 128 threads, 8x8 register tile per thread.
template<int K, bool CONCAT2>
__global__ __launch_bounds__(128) void k_rowmlp(const float* __restrict__ in1,
                                                const float* __restrict__ in2,
                                                const float* __restrict__ W,
                                                const float* __restrict__ bias,
                                                float* __restrict__ out)
{
    __shared__ float Ws[K * HD];     // [K][128] as-is (row-major)
    __shared__ float hsb[64 * K];    // 64 input rows, granule-XOR-swizzled
    const int t = threadIdx.x;
    const int row0 = blockIdx.x * 64;
    const int rg = t >> 4;           // 0..7 -> rows rg*8..+8
    const int dg = t & 15;           // 0..15 -> d dg*8..+8
    const int r0 = rg * 8, d0 = dg * 8;

    float acc[8][8];
#pragma unroll
    for (int u = 0; u < 8; ++u)
#pragma unroll
        for (int v = 0; v < 8; ++v) acc[u][v] = 0.f;

    const int NPH = CONCAT2 ? 2 : 1;
    for (int ph = 0; ph < NPH; ++ph) {
        const float* src = ph ? in2 : in1;
        const float* Wp  = W + (size_t)ph * K * HD;
        if (ph) __syncthreads();
        // stage W (flat copy, coalesced)
        for (int c = t; c < K * 32; c += 128)
            *(float4*)&Ws[c * 4] = ld4(&Wp[(size_t)c * 4]);
        // stage 64 input rows, swizzled: granule g -> g ^ ((r>>3)&7)
        for (int c = t; c < K * 16; c += 128) {
            int r = c / (K / 4);
            int g = c % (K / 4);
            float4 v = ld4(&src[(size_t)(row0 + r) * K + g * 4]);
            int gs = g ^ ((r >> 3) & 7);
            *(float4*)&hsb[r * K + gs * 4] = v;
        }
        __syncthreads();
        for (int k = 0; k < K; k += 4) {
            float4 hv[8];
#pragma unroll
            for (int u = 0; u < 8; ++u) {
                int gs = (k >> 2) ^ (((r0 + u) >> 3) & 7);
                hv[u] = ld4(&hsb[(r0 + u) * K + gs * 4]);
            }
#pragma unroll
            for (int kk = 0; kk < 4; ++kk) {
                float4 wa = ld4(&Ws[(k + kk) * HD + d0]);
                float4 wb = ld4(&Ws[(k + kk) * HD + d0 + 4]);
#pragma unroll
                for (int u = 0; u < 8; ++u) {
                    float hval = ((const float*)&hv[u])[kk];
                    acc[u][0] = fmaf(hval, wa.x, acc[u][0]);
                    acc[u][1] = fmaf(hval, wa.y, acc[u][1]);
                    acc[u][2] = fmaf(hval, wa.z, acc[u][2]);
                    acc[u][3] = fmaf(hval, wa.w, acc[u][3]);
                    acc[u][4] = fmaf(hval, wb.x, acc[u][4]);
                    acc[u][5] = fmaf(hval, wb.y, acc[u][5]);
                    acc[u][6] = fmaf(hval, wb.z, acc[u][6]);
                    acc[u][7] = fmaf(hval, wb.w, acc[u][7]);
                }
            }
        }
    }
    float b0[8];
#pragma unroll
    for (int v = 0; v < 8; ++v) b0[v] = bias[d0 + v];
#pragma unroll
    for (int u = 0; u < 8; ++u) {
        float4 o0, o1;
        o0.x = fmaxf(acc[u][0] + b0[0], 0.f);
        o0.y = fmaxf(acc[u][1] + b0[1], 0.f);
        o0.z = fmaxf(acc[u][2] + b0[2], 0.f);
        o0.w = fmaxf(acc[u][3] + b0[3], 0.f);
        o1.x = fmaxf(acc[u][4] + b0[4], 0.f);
        o1.y = fmaxf(acc[u][5] + b0[5], 0.f);
        o1.z = fmaxf(acc[u][6] + b0[6], 0.f);
        o1.w = fmaxf(acc[u][7] + b0[7], 0.f);
        float* op = &out[(size_t)(row0 + r0 + u) * HD + d0];
        *(float4*)op = o0;
        *(float4*)(op + 4) = o1;
    }
}

// -------------- m = softmax(A, axis=-1) @ msg , fused; 16 rows/block --------------
template<bool FORMULA>
__global__ __launch_bounds__(256) void k_smax_agg(const float* __restrict__ A,
                                                  const float* __restrict__ msg,
                                                  float* __restrict__ mout)
{
    __shared__ float p[TI][NN + 4];
    __shared__ float inv_s[TI];
    const int t = threadIdx.x;
    const int b = blockIdx.x >> 6;            // 64 tiles per batch
    const int i0 = (blockIdx.x & 63) * TI;

    // ---- load A tile (or compute |i-j|+1 analytically for iteration 0) ----
    if (FORMULA) {
        for (int r = 0; r < TI; ++r) {
            int i = i0 + r;
            for (int j = t; j < NN; j += 256) {
                int di = i - j;
                p[r][j] = (float)(di < 0 ? -di : di) + 1.0f;
            }
        }
    } else {
        const float* Ab = A + ((size_t)b * NN + i0) * NN;
        for (int r = 0; r < TI; ++r) {
            int j = t * 4;
            *(float4*)&p[r][j] = ld4(&Ab[(size_t)r * NN + j]);
        }
    }
    __syncthreads();

    // ---- per-row softmax: wave w owns rows w*4 .. w*4+3 ----
    const int wave = t >> 6, lane = t & 63;
    for (int rr = 0; rr < 4; ++rr) {
        int r = wave * 4 + rr;
        float pv[16];
#pragma unroll
        for (int jj = 0; jj < 16; ++jj) pv[jj] = p[r][lane + 64 * jj];
        float mx = pv[0];
#pragma unroll
        for (int jj = 1; jj < 16; ++jj) mx = fmaxf(mx, pv[jj]);
#pragma unroll
        for (int off = 32; off > 0; off >>= 1) mx = fmaxf(mx, __shfl_down(mx, off));
        mx = __shfl(mx, 0);
        float s = 0.f;
#pragma unroll
        for (int jj = 0; jj < 16; ++jj) {
            float e = __expf(pv[jj] - mx);
            p[r][lane + 64 * jj] = e;
            s += e;
        }
#pragma unroll
        for (int off = 32; off > 0; off >>= 1) s += __shfl_down(s, off);
        if (lane == 0) inv_s[r] = 1.0f / s;
    }
    __syncthreads();

    // ---- aggregation: j split in 4 quarters; thread owns 4 rows x 8 d ----
    const int q  = t >> 6;
    const int tq = t & 63;
    const int r0 = (tq >> 4) * 4;
    const int d0 = (tq & 15) * 8;
    float acc[4][8];
#pragma unroll
    for (int rr = 0; rr < 4; ++rr)
#pragma unroll
        for (int dd = 0; dd < 8; ++dd) acc[rr][dd] = 0.f;

    const float* msgb = msg + (size_t)b * NN * HD;
    for (int j4 = q * 256; j4 < q * 256 + 256; j4 += 4) {
        float4 pr[4];
#pragma unroll
        for (int rr = 0; rr < 4; ++rr) pr[rr] = ld4(&p[r0 + rr][j4]);
#pragma unroll
        for (int jj = 0; jj < 4; ++jj) {
            float4 m0 = ld4(&msgb[(size_t)(j4 + jj) * HD + d0]);
            float4 m1 = ld4(&msgb[(size_t)(j4 + jj) * HD + d0 + 4]);
#pragma unroll
            for (int rr = 0; rr < 4; ++rr) {
                float pw = ((const float*)&pr[rr])[jj];
                acc[rr][0] = fmaf(pw, m0.x, acc[rr][0]);
                acc[rr][1] = fmaf(pw, m0.y, acc[rr][1]);
                acc[rr][2] = fmaf(pw, m0.z, acc[rr][2]);
                acc[rr][3] = fmaf(pw, m0.w, acc[rr][3]);
                acc[rr][4] = fmaf(pw, m1.x, acc[rr][4]);
                acc[rr][5] = fmaf(pw, m1.y, acc[rr][5]);
                acc[rr][6] = fmaf(pw, m1.z, acc[rr][6]);
                acc[rr][7] = fmaf(pw, m1.w, acc[rr][7]);
            }
        }
    }
    __syncthreads();
    // reduce the 4 j-quarters through LDS (alias p; all reads of p are done)
    float* redbuf = &p[0][0];          // [4][TI][HD] = 32 KB
#pragma unroll
    for (int rr = 0; rr < 4; ++rr) {
        float* rp = &redbuf[((q * TI) + r0 + rr) * HD + d0];
        *(float4*)rp       = make_float4(acc[rr][0], acc[rr][1], acc[rr][2], acc[rr][3]);
        *(float4*)(rp + 4) = make_float4(acc[rr][4], acc[rr][5], acc[rr][6], acc[rr][7]);
    }
    __syncthreads();
#pragma unroll
    for (int kk = 0; kk < 8; ++kk) {
        int o = t + 256 * kk;
        int r = o >> 7, d = o & 127;
        float s = redbuf[r * HD + d] + redbuf[(TI + r) * HD + d]
                + redbuf[(2 * TI + r) * HD + d] + redbuf[(3 * TI + r) * HD + d];
        mout[((size_t)b * NN + i0 + r) * HD + d] = s * inv_s[r];
    }
}

// -------------- A = h @ h^T / sqrt(128); 64x64 tile, 8x4 per thread --------------
__device__ __forceinline__ int aswz(int r, int k) {
    return r * HD + ((((k >> 2) ^ ((r >> 2) & 7)) << 2) | (k & 3));
}

__global__ __launch_bounds__(128) void k_anew(const float* __restrict__ h,
                                              float* __restrict__ A)
{
    __shared__ float sa[64 * HD];
    __shared__ float sb[64 * HD];
    const int t = threadIdx.x;
    const int b = blockIdx.z;
    const int i0 = blockIdx.y * 64;
    const int j0 = blockIdx.x * 64;
    const float* hb = h + (size_t)b * NN * HD;

    for (int c = t; c < 2048; c += 128) {
        int r = c >> 5;
        int k = (c & 31) * 4;
        float4 va = ld4(&hb[(size_t)(i0 + r) * HD + k]);
        *(float4*)&sa[aswz(r, k)] = va;
        float4 vb = ld4(&hb[(size_t)(j0 + r) * HD + k]);
        *(float4*)&sb[aswz(r, k)] = vb;
    }
    __syncthreads();

    const int tx = t & 15, ty = t >> 4;   // ty 0..7
    float acc[8][4];
#pragma unroll
    for (int u = 0; u < 8; ++u)
#pragma unroll
        for (int v = 0; v < 4; ++v) acc[u][v] = 0.f;

    for (int k = 0; k < HD; k += 4) {
        float4 av[8], bv[4];
#pragma unroll
        for (int u = 0; u < 8; ++u) av[u] = ld4(&sa[aswz(ty * 8 + u, k)]);
#pragma unroll
        for (int v = 0; v < 4; ++v) bv[v] = ld4(&sb[aswz(tx * 4 + v, k)]);
#pragma unroll
        for (int kk = 0; kk < 4; ++kk) {
#pragma unroll
            for (int u = 0; u < 8; ++u) {
                float a = ((const float*)&av[u])[kk];
#pragma unroll
                for (int v = 0; v < 4; ++v) {
                    float bb = ((const float*)&bv[v])[kk];
                    acc[u][v] = fmaf(a, bb, acc[u][v]);
                }
            }
        }
    }
    const float scale = 0.08838834764831845f;  // 1/sqrt(128)
#pragma unroll
    for (int u = 0; u < 8; ++u) {
        float4 o;
        o.x = acc[u][0] * scale;
        o.y = acc[u][1] * scale;
        o.z = acc[u][2] * scale;
        o.w = acc[u][3] * scale;
        *(float4*)&A[((size_t)b * NN + i0 + ty * 8 + u) * NN + j0 + tx * 4] = o;
    }
}

extern "C" void kernel_launch(void* const* d_in, const int* in_sizes, int n_in,
                              void* d_out, int out_size, void* d_ws, size_t ws_size,
                              hipStream_t stream)
{
    const float* x   = (const float*)d_in[0];
    const float* We0 = (const float*)d_in[1];
    const float* be0 = (const float*)d_in[2];
    const float* We1 = (const float*)d_in[3];
    const float* be1 = (const float*)d_in[4];
    const float* Wm  = (const float*)d_in[5];
    const float* bm  = (const float*)d_in[6];
    const float* Wu  = (const float*)d_in[7];
    const float* bu  = (const float*)d_in[8];
    float* out = (float*)d_out;

    char* ws = (char*)d_ws;
    float* A   = (float*)ws;                                   // 67 MB
    float* h   = (float*)(ws + (size_t)BSZ * NN * NN * 4);     // 8 MB
    float* msg = h + (size_t)BSZ * NN * HD;                    // 8 MB
    float* m   = msg + (size_t)BSZ * NN * HD;                  // 8 MB

    const int nrow_blocks = BSZ * NN / 64;                     // 256

    // embedding MLP
    k_rowmlp<FE, false><<<nrow_blocks, 128, 0, stream>>>(x, nullptr, We0, be0, h);
    k_rowmlp<HD, false><<<nrow_blocks, 128, 0, stream>>>(h, nullptr, We1, be1, h);

    for (int k = 0; k < NIT; ++k) {
        // msg = relu(h @ Wm[k] + bm[k])
        k_rowmlp<HD, false><<<nrow_blocks, 128, 0, stream>>>(
            h, nullptr, Wm + (size_t)k * HD * HD, bm + (size_t)k * HD, msg);
        // m = softmax(A) @ msg   (iteration 0: A = |i-j|+1 analytically)
        if (k == 0)
            k_smax_agg<true><<<BSZ * NN / TI, 256, 0, stream>>>(nullptr, msg, m);
        else
            k_smax_agg<false><<<BSZ * NN / TI, 256, 0, stream>>>(A, msg, m);
        // h = relu(concat([h, m]) @ Wu[k] + bu[k])   (in-place, row-local)
        k_rowmlp<HD, true><<<nrow_blocks, 128, 0, stream>>>(
            h, m, Wu + (size_t)k * 2 * HD * HD, bu + (size_t)k * HD, h);
        // A = h @ h^T / sqrt(128)
        float* Aout = (k == NIT - 1) ? out : A;
        k_anew<<<dim3(NN / 64, NN / 64, BSZ), 128, 0, stream>>>(h, Aout);
    }
}

// Round 2
// 691.330 us; speedup vs baseline: 1.4562x; 1.4562x over previous
//
#include <hip/hip_runtime.h>

#define BSZ 16
#define NN 1024
#define FE 64
#define HD 128
#define NIT 4
#define TI 16

typedef unsigned short u16;
typedef __attribute__((ext_vector_type(8))) short bf16x8;
typedef __attribute__((ext_vector_type(4))) float f32x4;

__device__ __forceinline__ float4 ld4(const float* p) { return *(const float4*)p; }

__device__ __forceinline__ u16 f2bf_rne(float x) {
    unsigned int u = __float_as_uint(x);
    u += 0x7fffu + ((u >> 16) & 1u);
    return (u16)(u >> 16);
}
__device__ __forceinline__ float bf2f(u16 h) {
    return __uint_as_float(((unsigned int)h) << 16);
}

// ---------------- row-MLP: out[row,:] = relu( [in1(,in2)] @ W + b ) ----------------
template<int K, bool CONCAT2>
__global__ __launch_bounds__(128) void k_rowmlp(const float* __restrict__ in1,
                                                const float* __restrict__ in2,
                                                const float* __restrict__ W,
                                                const float* __restrict__ bias,
                                                float* __restrict__ out)
{
    __shared__ float Ws[K * HD];
    __shared__ float hsb[64 * K];
    const int t = threadIdx.x;
    const int row0 = blockIdx.x * 64;
    const int rg = t >> 4;
    const int dg = t & 15;
    const int r0 = rg * 8, d0 = dg * 8;

    float acc[8][8];
#pragma unroll
    for (int u = 0; u < 8; ++u)
#pragma unroll
        for (int v = 0; v < 8; ++v) acc[u][v] = 0.f;

    const int NPH = CONCAT2 ? 2 : 1;
    for (int ph = 0; ph < NPH; ++ph) {
        const float* src = ph ? in2 : in1;
        const float* Wp  = W + (size_t)ph * K * HD;
        if (ph) __syncthreads();
        for (int c = t; c < K * 32; c += 128)
            *(float4*)&Ws[c * 4] = ld4(&Wp[(size_t)c * 4]);
        for (int c = t; c < K * 16; c += 128) {
            int r = c / (K / 4);
            int g = c % (K / 4);
            float4 v = ld4(&src[(size_t)(row0 + r) * K + g * 4]);
            int gs = g ^ ((r >> 3) & 7);
            *(float4*)&hsb[r * K + gs * 4] = v;
        }
        __syncthreads();
        for (int k = 0; k < K; k += 4) {
            float4 hv[8];
#pragma unroll
            for (int u = 0; u < 8; ++u) {
                int gs = (k >> 2) ^ (((r0 + u) >> 3) & 7);
                hv[u] = ld4(&hsb[(r0 + u) * K + gs * 4]);
            }
#pragma unroll
            for (int kk = 0; kk < 4; ++kk) {
                float4 wa = ld4(&Ws[(k + kk) * HD + d0]);
                float4 wb = ld4(&Ws[(k + kk) * HD + d0 + 4]);
#pragma unroll
                for (int u = 0; u < 8; ++u) {
                    float hval = ((const float*)&hv[u])[kk];
                    acc[u][0] = fmaf(hval, wa.x, acc[u][0]);
                    acc[u][1] = fmaf(hval, wa.y, acc[u][1]);
                    acc[u][2] = fmaf(hval, wa.z, acc[u][2]);
                    acc[u][3] = fmaf(hval, wa.w, acc[u][3]);
                    acc[u][4] = fmaf(hval, wb.x, acc[u][4]);
                    acc[u][5] = fmaf(hval, wb.y, acc[u][5]);
                    acc[u][6] = fmaf(hval, wb.z, acc[u][6]);
                    acc[u][7] = fmaf(hval, wb.w, acc[u][7]);
                }
            }
        }
    }
    float b0[8];
#pragma unroll
    for (int v = 0; v < 8; ++v) b0[v] = bias[d0 + v];
#pragma unroll
    for (int u = 0; u < 8; ++u) {
        float4 o0, o1;
        o0.x = fmaxf(acc[u][0] + b0[0], 0.f);
        o0.y = fmaxf(acc[u][1] + b0[1], 0.f);
        o0.z = fmaxf(acc[u][2] + b0[2], 0.f);
        o0.w = fmaxf(acc[u][3] + b0[3], 0.f);
        o1.x = fmaxf(acc[u][4] + b0[4], 0.f);
        o1.y = fmaxf(acc[u][5] + b0[5], 0.f);
        o1.z = fmaxf(acc[u][6] + b0[6], 0.f);
        o1.w = fmaxf(acc[u][7] + b0[7], 0.f);
        float* op = &out[(size_t)(row0 + r0 + u) * HD + d0];
        *(float4*)op = o0;
        *(float4*)(op + 4) = o1;
    }
}

// -------------- m = softmax(A, axis=-1) @ msg , fused; 16 rows/block --------------
template<bool FORMULA>
__global__ __launch_bounds__(256) void k_smax_agg(const float* __restrict__ A,
                                                  const float* __restrict__ msg,
                                                  float* __restrict__ mout)
{
    __shared__ float p[TI][NN + 4];
    __shared__ float inv_s[TI];
    const int t = threadIdx.x;
    const int b = blockIdx.x >> 6;
    const int i0 = (blockIdx.x & 63) * TI;

    if (FORMULA) {
        for (int r = 0; r < TI; ++r) {
            int i = i0 + r;
            for (int j = t; j < NN; j += 256) {
                int di = i - j;
                p[r][j] = (float)(di < 0 ? -di : di) + 1.0f;
            }
        }
    } else {
        const float* Ab = A + ((size_t)b * NN + i0) * NN;
        for (int r = 0; r < TI; ++r) {
            int j = t * 4;
            *(float4*)&p[r][j] = ld4(&Ab[(size_t)r * NN + j]);
        }
    }
    __syncthreads();

    const int wave = t >> 6, lane = t & 63;
    for (int rr = 0; rr < 4; ++rr) {
        int r = wave * 4 + rr;
        float pv[16];
#pragma unroll
        for (int jj = 0; jj < 16; ++jj) pv[jj] = p[r][lane + 64 * jj];
        float mx = pv[0];
#pragma unroll
        for (int jj = 1; jj < 16; ++jj) mx = fmaxf(mx, pv[jj]);
#pragma unroll
        for (int off = 32; off > 0; off >>= 1) mx = fmaxf(mx, __shfl_down(mx, off));
        mx = __shfl(mx, 0);
        float s = 0.f;
#pragma unroll
        for (int jj = 0; jj < 16; ++jj) {
            float e = __expf(pv[jj] - mx);
            p[r][lane + 64 * jj] = e;
            s += e;
        }
#pragma unroll
        for (int off = 32; off > 0; off >>= 1) s += __shfl_down(s, off);
        if (lane == 0) inv_s[r] = 1.0f / s;
    }
    __syncthreads();

    const int q  = t >> 6;
    const int tq = t & 63;
    const int r0 = (tq >> 4) * 4;
    const int d0 = (tq & 15) * 8;
    float acc[4][8];
#pragma unroll
    for (int rr = 0; rr < 4; ++rr)
#pragma unroll
        for (int dd = 0; dd < 8; ++dd) acc[rr][dd] = 0.f;

    const float* msgb = msg + (size_t)b * NN * HD;
    for (int j4 = q * 256; j4 < q * 256 + 256; j4 += 4) {
        float4 pr[4];
#pragma unroll
        for (int rr = 0; rr < 4; ++rr) pr[rr] = ld4(&p[r0 + rr][j4]);
#pragma unroll
        for (int jj = 0; jj < 4; ++jj) {
            float4 m0 = ld4(&msgb[(size_t)(j4 + jj) * HD + d0]);
            float4 m1 = ld4(&msgb[(size_t)(j4 + jj) * HD + d0 + 4]);
#pragma unroll
            for (int rr = 0; rr < 4; ++rr) {
                float pw = ((const float*)&pr[rr])[jj];
                acc[rr][0] = fmaf(pw, m0.x, acc[rr][0]);
                acc[rr][1] = fmaf(pw, m0.y, acc[rr][1]);
                acc[rr][2] = fmaf(pw, m0.z, acc[rr][2]);
                acc[rr][3] = fmaf(pw, m0.w, acc[rr][3]);
                acc[rr][4] = fmaf(pw, m1.x, acc[rr][4]);
                acc[rr][5] = fmaf(pw, m1.y, acc[rr][5]);
                acc[rr][6] = fmaf(pw, m1.z, acc[rr][6]);
                acc[rr][7] = fmaf(pw, m1.w, acc[rr][7]);
            }
        }
    }
    __syncthreads();
    float* redbuf = &p[0][0];
#pragma unroll
    for (int rr = 0; rr < 4; ++rr) {
        float* rp = &redbuf[((q * TI) + r0 + rr) * HD + d0];
        *(float4*)rp       = make_float4(acc[rr][0], acc[rr][1], acc[rr][2], acc[rr][3]);
        *(float4*)(rp + 4) = make_float4(acc[rr][4], acc[rr][5], acc[rr][6], acc[rr][7]);
    }
    __syncthreads();
#pragma unroll
    for (int kk = 0; kk < 8; ++kk) {
        int o = t + 256 * kk;
        int r = o >> 7, d = o & 127;
        float s = redbuf[r * HD + d] + redbuf[(TI + r) * HD + d]
                + redbuf[(2 * TI + r) * HD + d] + redbuf[(3 * TI + r) * HD + d];
        mout[((size_t)b * NN + i0 + r) * HD + d] = s * inv_s[r];
    }
}

// -------------- split h (fp32) -> [hi | lo] bf16, K=256 per row --------------
__global__ __launch_bounds__(256) void k_split(const float* __restrict__ h,
                                               u16* __restrict__ hs)
{
    int i = blockIdx.x * 256 + threadIdx.x;        // one float4 per thread
    float4 v = ld4(&h[(size_t)i * 4]);
    size_t row = (size_t)(i >> 5);
    int d = (i & 31) * 4;
    u16 hi[4], lo[4];
    float xs[4] = {v.x, v.y, v.z, v.w};
#pragma unroll
    for (int k = 0; k < 4; ++k) {
        hi[k] = f2bf_rne(xs[k]);
        lo[k] = f2bf_rne(xs[k] - bf2f(hi[k]));
    }
    uint2 uh, ul;
    uh.x = (unsigned)hi[0] | ((unsigned)hi[1] << 16);
    uh.y = (unsigned)hi[2] | ((unsigned)hi[3] << 16);
    ul.x = (unsigned)lo[0] | ((unsigned)lo[1] << 16);
    ul.y = (unsigned)lo[2] | ((unsigned)lo[3] << 16);
    *(uint2*)&hs[row * 256 + d]       = uh;
    *(uint2*)&hs[row * 256 + 128 + d] = ul;
}

// -------------- A = h @ h^T / sqrt(128) via bf16 MFMA on [hi|lo] (K=256) --------------
__global__ __launch_bounds__(256) void k_anew_mfma(const u16* __restrict__ hs,
                                                   float* __restrict__ A)
{
    __shared__ u16 sa[128 * 64];
    __shared__ u16 sb[128 * 64];
    const int t = threadIdx.x;
    const int wave = t >> 6, lane = t & 63;
    const int b = blockIdx.z;
    const int i0 = blockIdx.y * 128;
    const int j0 = blockIdx.x * 128;
    const u16* hb = hs + (size_t)b * NN * 256;

    const int wr = wave >> 1, wc = wave & 1;

    f32x4 acc[4][4];
#pragma unroll
    for (int m = 0; m < 4; ++m)
#pragma unroll
        for (int n = 0; n < 4; ++n) acc[m][n] = (f32x4){0.f, 0.f, 0.f, 0.f};

    // staging: 4 chunks (16B) each for sa and sb per thread; swizzle c ^= (r&7)
    const int ch_r[4] = { (0 * 256 + t) >> 3, (1 * 256 + t) >> 3,
                          (2 * 256 + t) >> 3, (3 * 256 + t) >> 3 };
    const int ch_c = t & 7;  // c = (s*256+t)&7 == t&7 for all s

#define STAGE(step)                                                            \
    {                                                                          \
        uint4 va[4], vb[4];                                                    \
        _Pragma("unroll")                                                      \
        for (int s = 0; s < 4; ++s) {                                          \
            int r = ch_r[s];                                                   \
            const u16* ga = hb + (size_t)(i0 + r) * 256 + (step) * 64 + ch_c * 8; \
            const u16* gb = hb + (size_t)(j0 + r) * 256 + (step) * 64 + ch_c * 8; \
            va[s] = *(const uint4*)ga;                                         \
            vb[s] = *(const uint4*)gb;                                         \
        }                                                                      \
        _Pragma("unroll")                                                      \
        for (int s = 0; s < 4; ++s) {                                          \
            int r = ch_r[s];                                                   \
            int swz = (ch_c ^ (r & 7)) * 8;                                    \
            *(uint4*)&sa[r * 64 + swz] = va[s];                                \
            *(uint4*)&sb[r * 64 + swz] = vb[s];                                \
        }                                                                      \
    }

    STAGE(0);
    __syncthreads();

    for (int step = 0; step < 4; ++step) {
#pragma unroll
        for (int ks = 0; ks < 2; ++ks) {
            const int chunk = ks * 4 + (lane >> 4);
            bf16x8 af[4], bfr[4];
#pragma unroll
            for (int m = 0; m < 4; ++m) {
                int row = wr * 64 + m * 16 + (lane & 15);
                af[m] = *(const bf16x8*)&sa[row * 64 + ((chunk ^ (row & 7)) * 8)];
            }
#pragma unroll
            for (int n = 0; n < 4; ++n) {
                int row = wc * 64 + n * 16 + (lane & 15);
                bfr[n] = *(const bf16x8*)&sb[row * 64 + ((chunk ^ (row & 7)) * 8)];
            }
#pragma unroll
            for (int m = 0; m < 4; ++m)
#pragma unroll
                for (int n = 0; n < 4; ++n)
                    acc[m][n] = __builtin_amdgcn_mfma_f32_16x16x32_bf16(
                        af[m], bfr[n], acc[m][n], 0, 0, 0);
        }
        if (step < 3) {
            __syncthreads();
            STAGE(step + 1);
            __syncthreads();
        }
    }
#undef STAGE

    // store: value(lane,reg) = A[i0+wr*64+m*16+(lane>>4)*4+reg][j0+wc*64+n*16+(lane&15)]
    // A symmetric -> store transposed position as contiguous float4
    const float scale = 0.08838834764831845f;
#pragma unroll
    for (int m = 0; m < 4; ++m) {
        int col = i0 + wr * 64 + m * 16 + (lane >> 4) * 4;
#pragma unroll
        for (int n = 0; n < 4; ++n) {
            int row = j0 + wc * 64 + n * 16 + (lane & 15);
            float4 o;
            o.x = acc[m][n][0] * scale;
            o.y = acc[m][n][1] * scale;
            o.z = acc[m][n][2] * scale;
            o.w = acc[m][n][3] * scale;
            *(float4*)&A[((size_t)b * NN + row) * NN + col] = o;
        }
    }
}

extern "C" void kernel_launch(void* const* d_in, const int* in_sizes, int n_in,
                              void* d_out, int out_size, void* d_ws, size_t ws_size,
                              hipStream_t stream)
{
    const float* x   = (const float*)d_in[0];
    const float* We0 = (const float*)d_in[1];
    const float* be0 = (const float*)d_in[2];
    const float* We1 = (const float*)d_in[3];
    const float* be1 = (const float*)d_in[4];
    const float* Wm  = (const float*)d_in[5];
    const float* bm  = (const float*)d_in[6];
    const float* Wu  = (const float*)d_in[7];
    const float* bu  = (const float*)d_in[8];
    float* out = (float*)d_out;

    char* ws = (char*)d_ws;
    float* A   = (float*)ws;                                   // 67 MB
    float* h   = (float*)(ws + (size_t)BSZ * NN * NN * 4);     // 8 MB
    float* msg = h + (size_t)BSZ * NN * HD;                    // 8 MB
    float* m   = msg + (size_t)BSZ * NN * HD;                  // 8 MB
    u16* hsplit = (u16*)msg;   // overlay: msg dead once k_split runs (same byte size)

    const int nrow_blocks = BSZ * NN / 64;                     // 256
    const int nsplit_blocks = BSZ * NN * HD / 4 / 256;         // 2048

    // embedding MLP
    k_rowmlp<FE, false><<<nrow_blocks, 128, 0, stream>>>(x, nullptr, We0, be0, h);
    k_rowmlp<HD, false><<<nrow_blocks, 128, 0, stream>>>(h, nullptr, We1, be1, h);

    for (int k = 0; k < NIT; ++k) {
        // msg = relu(h @ Wm[k] + bm[k])
        k_rowmlp<HD, false><<<nrow_blocks, 128, 0, stream>>>(
            h, nullptr, Wm + (size_t)k * HD * HD, bm + (size_t)k * HD, msg);
        // m = softmax(A) @ msg   (iteration 0: A = |i-j|+1 analytically)
        if (k == 0)
            k_smax_agg<true><<<BSZ * NN / TI, 256, 0, stream>>>(nullptr, msg, m);
        else
            k_smax_agg<false><<<BSZ * NN / TI, 256, 0, stream>>>(A, msg, m);
        // h = relu(concat([h, m]) @ Wu[k] + bu[k])   (in-place, row-local)
        k_rowmlp<HD, true><<<nrow_blocks, 128, 0, stream>>>(
            h, m, Wu + (size_t)k * 2 * HD * HD, bu + (size_t)k * HD, h);
        // hsplit = [bf16_hi(h) | bf16_lo(h)]  (overlays msg, which is dead now)
        k_split<<<nsplit_blocks, 256, 0, stream>>>(h, hsplit);
        // A = h @ h^T / sqrt(128) via bf16-split MFMA
        float* Aout = (k == NIT - 1) ? out : A;
        k_anew_mfma<<<dim3(NN / 128, NN / 128, BSZ), 256, 0, stream>>>(hsplit, Aout);
    }
}